// Round 1
// baseline (351.162 us; speedup 1.0000x reference)
//
#include <hip/hip_runtime.h>
#include <hip/hip_bf16.h>

// score[t] = dot(emb[s[t]], W[r[t], :512]) + dot(emb[o[t]], W[r[t], 512:]) + b[r[t]]
// One 64-lane wave per triple; fully-coalesced float4 row loads; shfl reduce.

#define NDIM 512          // embedding dim
#define NV4  (NDIM / 4)   // 128 float4 per row

__global__ __launch_bounds__(256) void kg_score_kernel(
    const float* __restrict__ emb,      // [N_NODES, 512]
    const float* __restrict__ W,        // [N_REL, 1024]
    const float* __restrict__ b,        // [N_REL]
    const int*   __restrict__ triples,  // [3, T] row-major: s | r | o
    float*       __restrict__ out,      // [T]
    int T)
{
    const int wid  = (int)((blockIdx.x * (unsigned)blockDim.x + threadIdx.x) >> 6);
    const int lane = threadIdx.x & 63;
    if (wid >= T) return;

    const int s = triples[wid];
    const int r = triples[T + wid];
    const int o = triples[2 * T + wid];

    const float4* __restrict__ srow = (const float4*)(emb + (long)s * NDIM);
    const float4* __restrict__ orow = (const float4*)(emb + (long)o * NDIM);
    const float4* __restrict__ wsrow = (const float4*)(W + (long)r * (2 * NDIM));
    const float4* __restrict__ worow = wsrow + NV4;   // second half of W row

    float acc = 0.0f;
#pragma unroll
    for (int k = 0; k < 2; ++k) {
        const int idx = lane + k * 64;     // covers 0..127 float4
        float4 sv = srow[idx];
        float4 wv = wsrow[idx];
        acc = fmaf(sv.x, wv.x, acc);
        acc = fmaf(sv.y, wv.y, acc);
        acc = fmaf(sv.z, wv.z, acc);
        acc = fmaf(sv.w, wv.w, acc);
        float4 ov = orow[idx];
        float4 uv = worow[idx];
        acc = fmaf(ov.x, uv.x, acc);
        acc = fmaf(ov.y, uv.y, acc);
        acc = fmaf(ov.z, uv.z, acc);
        acc = fmaf(ov.w, uv.w, acc);
    }

    // 64-lane butterfly reduction
#pragma unroll
    for (int off = 32; off > 0; off >>= 1)
        acc += __shfl_xor(acc, off, 64);

    if (lane == 0)
        out[wid] = acc + b[r];
}

extern "C" void kernel_launch(void* const* d_in, const int* in_sizes, int n_in,
                              void* d_out, int out_size, void* d_ws, size_t ws_size,
                              hipStream_t stream)
{
    const float* emb     = (const float*)d_in[0];
    const float* W       = (const float*)d_in[1];
    const float* b       = (const float*)d_in[2];
    const int*   triples = (const int*)d_in[3];
    float*       out     = (float*)d_out;

    const int T = in_sizes[3] / 3;          // triples is [3, T]

    const int block = 256;                  // 4 waves/block, 1 wave/triple
    const int wavesPerBlock = block / 64;
    const int grid = (T + wavesPerBlock - 1) / wavesPerBlock;

    kg_score_kernel<<<grid, block, 0, stream>>>(emb, W, b, triples, out, T);
}